// Round 13
// baseline (116.553 us; speedup 1.0000x reference)
//
#include <hip/hip_runtime.h>
#include <hip/hip_bf16.h>
#include <cstdint>

// x: [8,8192,512] f32 -> LN over E=512 -> h=[16384,2048] bf16 (row-major flatten)
// W: [2048,512] f32, b: [512]; out = gelu(h @ W' + b'),
// W' = gamma-folded W (bf16, transposed), b' = b + beta @ W.
#define XROWS   65536
#define E       512
#define MROWS   16384
#define KDIM    2048
#define NDIM    512
#define NT      32        // K-steps of 64

typedef __attribute__((ext_vector_type(4))) float f32x4;
typedef __attribute__((ext_vector_type(8))) unsigned short u16x8;
typedef __attribute__((ext_vector_type(8))) __bf16 bf16x8;

__device__ __forceinline__ unsigned short f2bf(float f) {
  unsigned u = __builtin_bit_cast(unsigned, f);
  u += 0x7FFFu + ((u >> 16) & 1u);   // round-to-nearest-even
  return (unsigned short)(u >> 16);
}

typedef const __attribute__((address_space(1))) unsigned char ga_u8;
typedef __attribute__((address_space(3))) unsigned char ls_u8;
__device__ __forceinline__ void gload16(const void* g, void* l) {
  __builtin_amdgcn_global_load_lds((ga_u8*)g, (ls_u8*)l, 16, 0, 0);
}

// fast gelu (tanh form), |err vs erf form| <= ~3e-3 << 0.094 threshold
__device__ __forceinline__ float gelu_f(float v) {
  float p = v * (2.3022083f + 0.1029432f * (v * v));
  p = fminf(p, 80.0f);
  const float Ee = exp2f(p);
  return v * Ee * __builtin_amdgcn_rcpf(Ee + 1.0f);
}

// ---------------------------------------------------------------------------
// Merged setup: blocks 0..255 -> WT transpose+gamma-fold; 256..287 -> beta
// partials.  WT[n][k] = bf16(gamma[k%512] * W[k][n])
// ---------------------------------------------------------------------------
__global__ __launch_bounds__(256) void setup_kernel(const float* __restrict__ W,
                                                    const float* __restrict__ gamma,
                                                    const float* __restrict__ beta,
                                                    unsigned short* __restrict__ WT,
                                                    float* __restrict__ partial) {
  __shared__ float tile[64][68];
  const int t = threadIdx.x;
  if (blockIdx.x >= 256) {           // beta-fold partials
    const int bk = blockIdx.x - 256;
    float a0 = 0.f, a1 = 0.f;
    for (int k = 0; k < 64; ++k) {
      const int kg = bk * 64 + k;
      const float be = beta[kg & (E - 1)];
      a0 += be * W[(size_t)kg * NDIM + t];
      a1 += be * W[(size_t)kg * NDIM + 256 + t];
    }
    partial[bk * NDIM + t] = a0;
    partial[bk * NDIM + 256 + t] = a1;
    return;
  }
  const int bk = blockIdx.x >> 3;
  const int bn = blockIdx.x & 7;
  const int c4 = (t & 15) * 4;
#pragma unroll
  for (int i = 0; i < 4; ++i) {
    const int r = (t >> 4) + i * 16;
    const f32x4 v = *(const f32x4*)&W[(size_t)(bk * 64 + r) * NDIM + bn * 64 + c4];
    tile[r][c4 + 0] = v.x; tile[r][c4 + 1] = v.y;
    tile[r][c4 + 2] = v.z; tile[r][c4 + 3] = v.w;
  }
  __syncthreads();
#pragma unroll
  for (int j = 0; j < 2; ++j) {
    const int n  = j * 32 + (t >> 3);
    const int kb = (t & 7) * 8;
    const int kg0 = (bk & 7) * 64 + kb;
    const f32x4 g0 = *(const f32x4*)(gamma + kg0);
    const f32x4 g1 = *(const f32x4*)(gamma + kg0 + 4);
    const float gg[8] = {g0.x, g0.y, g0.z, g0.w, g1.x, g1.y, g1.z, g1.w};
    u16x8 o;
#pragma unroll
    for (int q = 0; q < 8; ++q) o[q] = f2bf(gg[q] * tile[kb + q][n]);
    *(u16x8*)&WT[(size_t)(bn * 64 + n) * KDIM + bk * 64 + kb] = o;
  }
}

__global__ __launch_bounds__(256) void kbias2(const float* __restrict__ b,
                                              const float* __restrict__ partial,
                                              float* __restrict__ biasf) {
  const int c = blockIdx.x * 256 + threadIdx.x;
  float s = b[c];
  for (int j = 0; j < 32; ++j) s += partial[j * NDIM + c];
  biasf[c] = s;
}

// ---------------------------------------------------------------------------
// LayerNorm: one wave per TWO x-rows of 512 f32 -> bf16 h (R10-proven, at
// its BW floor ~31us).
// ---------------------------------------------------------------------------
__global__ __launch_bounds__(256, 4) void ln_kernel(const float* __restrict__ x,
                                                    unsigned short* __restrict__ h) {
  const int w = threadIdx.x >> 6, l = threadIdx.x & 63;
  const size_t row = (size_t)blockIdx.x * 8 + w * 2;   // rows row, row+1
  const float* xr = x + row * E + l * 8;
  const f32x4 a0 = *(const f32x4*)xr;
  const f32x4 a1 = *(const f32x4*)(xr + 4);
  const f32x4 b0 = *(const f32x4*)(xr + E);
  const f32x4 b1 = *(const f32x4*)(xr + E + 4);
  float av[8] = {a0.x, a0.y, a0.z, a0.w, a1.x, a1.y, a1.z, a1.w};
  float bv[8] = {b0.x, b0.y, b0.z, b0.w, b1.x, b1.y, b1.z, b1.w};
  float s0 = 0.f, q0 = 0.f, s1 = 0.f, q1 = 0.f;
#pragma unroll
  for (int j = 0; j < 8; ++j) {
    s0 += av[j]; q0 += av[j] * av[j];
    s1 += bv[j]; q1 += bv[j] * bv[j];
  }
#pragma unroll
  for (int off = 32; off > 0; off >>= 1) {
    s0 += __shfl_xor(s0, off); q0 += __shfl_xor(q0, off);
    s1 += __shfl_xor(s1, off); q1 += __shfl_xor(q1, off);
  }
  const float mean0 = s0 * (1.0f / E);
  const float rstd0 = rsqrtf(q0 * (1.0f / E) - mean0 * mean0 + 1e-6f);
  const float nm0   = -mean0 * rstd0;
  const float mean1 = s1 * (1.0f / E);
  const float rstd1 = rsqrtf(q1 * (1.0f / E) - mean1 * mean1 + 1e-6f);
  const float nm1   = -mean1 * rstd1;
  u16x8 o0, o1;
#pragma unroll
  for (int j = 0; j < 8; ++j) {
    o0[j] = f2bf(av[j] * rstd0 + nm0);
    o1[j] = f2bf(bv[j] * rstd1 + nm1);
  }
  *(u16x8*)(h + row * E + l * 8) = o0;
  *(u16x8*)(h + (row + 1) * E + l * 8) = o1;
}

// ---------------------------------------------------------------------------
// GEMM, B-IN-REGISTERS variant (cuts the measured LDS-bytes bottleneck):
// 128x128 tile, BK=64, 4 waves (2x2, 64x64/wave), champion 2-barrier K-step.
// A: h via gload_lds into a single 16KB buffer (pre-swizzled source, T2 XOR
//    on ds_read) -- unchanged champion path.
// B: WT is 2MB = L2-resident (XCD-chunked grid) -> fragments loaded
//    global->VGPR ONE STEP AHEAD, issued after the compute-phase barrier so
//    they fly across the next barrier pair (cover = full MFMA+stage phases);
//    the next barrier's vmcnt(0) drain guarantees landing before use.
// Per-lane B address algebra == champion's swizzled ds_read (verified):
//    bv(n,kk)(t) = WT[brow0+wc*64+n*16+l15][t*64 + kk*32 + lhi*8 ..+8]
// -> bit-identical MFMA inputs -> absmax must stay 0.03125.
// LDS/block-step: 96KB -> 48KB. bvE/bvO double-buffer, fully unrolled.
// ---------------------------------------------------------------------------
__global__ __launch_bounds__(256, 2) void gemm_kernel(const unsigned short* __restrict__ A,
                                                      const unsigned short* __restrict__ Bt,
                                                      const float* __restrict__ biasf,
                                                      float* __restrict__ out) {
  __shared__ char smem[16384];   // A only: 128 rows x 128B (bf16, swizzled)
  const int tid = threadIdx.x;
  const int l = tid & 63, w = tid >> 6;
  const int l7 = l & 7, l15 = l & 15, lhi = l >> 4;
  const int wr = w >> 1, wc = w & 1;

  // XCD chunking: grid 512 = 8 XCDs x 64; bn in low 2 bits of wg
  const int wg = ((blockIdx.x & 7) << 6) | (blockIdx.x >> 3);
  const int bn = wg & 3;
  const int bm = wg >> 2;
  const size_t arow0 = (size_t)bm * 128;
  const int    brow0 = bn * 128;

  // A staging: thread covers rows {i*32 + w*8 + (l>>3)}, swizzled source col
  const int srow = w * 8 + (l >> 3);
  const int swz  = (l7 * 16) ^ ((l >> 3) << 4);
  const char* gA = (const char*)A + ((size_t)(arow0 + srow) * KDIM) * 2 + swz;

  // B fragment base: per-lane column (brow0 + wc*64 + n*16 + l15), k lhi*8
  const unsigned short* gBF = Bt + (size_t)(brow0 + wc * 64 + l15) * KDIM + lhi * 8;

  f32x4 acc[4][4];
#pragma unroll
  for (int m = 0; m < 4; ++m)
#pragma unroll
    for (int n = 0; n < 4; ++n) acc[m][n] = (f32x4){0.f, 0.f, 0.f, 0.f};

  // A-frag swizzled k-byte for kk=0; kk=1 flips bit 6 (outside swizzle)
  const int cs0 = (lhi * 16) ^ (l7 * 16);

  bf16x8 bvE[8], bvO[8];   // [kk*4+n], constant-indexed (fully unrolled)

#define LOADBV(BV, t)                                                          \
  _Pragma("unroll")                                                            \
  for (int kk = 0; kk < 2; ++kk)                                               \
    _Pragma("unroll")                                                          \
    for (int n = 0; n < 4; ++n)                                                \
      BV[kk * 4 + n] = *(const bf16x8*)(gBF + (size_t)n * 16 * KDIM +          \
                                        (t) * 64 + kk * 32)

#define STAGEA(t)                                                              \
  {                                                                            \
    const char* pa = gA + (size_t)(t) * 128;                                   \
    _Pragma("unroll")                                                          \
    for (int i = 0; i < 4; ++i)                                                \
      gload16(pa + (size_t)i * 32 * KDIM * 2, smem + (i * 32 + w * 8) * 128);  \
  }

#define COMPUTE(BV)                                                            \
  _Pragma("unroll")                                                            \
  for (int kk = 0; kk < 2; ++kk) {                                             \
    const int co = cs0 ^ (kk * 64);                                            \
    bf16x8 av[4];                                                              \
    _Pragma("unroll")                                                          \
    for (int m = 0; m < 4; ++m)                                                \
      av[m] = *(const bf16x8*)(smem + (wr * 64 + m * 16 + l15) * 128 + co);    \
    _Pragma("unroll")                                                          \
    for (int m = 0; m < 4; ++m)                                                \
      _Pragma("unroll")                                                        \
      for (int n = 0; n < 4; ++n)                                              \
        acc[m][n] = __builtin_amdgcn_mfma_f32_16x16x32_bf16(av[m],             \
                        BV[kk * 4 + n], acc[m][n], 0, 0, 0);                   \
  }

  LOADBV(bvE, 0);                 // bv(0); drained by iter-0's second barrier

  for (int t = 0; t < NT; t += 2) {
    // even step: compute with bvE; prefetch bvO(t+1) after the drain barrier
    __syncthreads();              // all waves done reading A(t-1)
    STAGEA(t);
    __syncthreads();              // A(t) visible (+ all in-flight B landed)
    if (t + 1 < NT) LOADBV(bvO, t + 1);   // rides across next barrier pair
    COMPUTE(bvE);
    // odd step: compute with bvO; prefetch bvE(t+2)
    __syncthreads();
    STAGEA(t + 1);
    __syncthreads();
    if (t + 2 < NT) LOADBV(bvE, t + 2);
    COMPUTE(bvO);
  }
#undef LOADBV
#undef STAGEA
#undef COMPUTE

  // epilogue: bias + fast gelu. C/D layout (m89): col = l&15, row = (l>>4)*4+reg
#pragma unroll
  for (int n = 0; n < 4; ++n) {
    const int col = brow0 + wc * 64 + n * 16 + l15;
    const float bb = biasf[col];
#pragma unroll
    for (int m = 0; m < 4; ++m) {
      const size_t rbase = arow0 + wr * 64 + m * 16 + lhi * 4;
#pragma unroll
      for (int r = 0; r < 4; ++r) {
        const float v = acc[m][n][r] + bb;
        out[(rbase + r) * NDIM + col] = gelu_f(v);
      }
    }
  }
}

// ---------------------------------------------------------------------------
extern "C" void kernel_launch(void* const* d_in, const int* in_sizes, int n_in,
                              void* d_out, int out_size, void* d_ws, size_t ws_size,
                              hipStream_t stream) {
  const float* x     = (const float*)d_in[0];
  const float* gamma = (const float*)d_in[1];
  const float* beta  = (const float*)d_in[2];
  const float* W     = (const float*)d_in[3];
  const float* b     = (const float*)d_in[4];
  float* out = (float*)d_out;

  // ws layout: WT 2MB | h 64MB | partial 64KB | biasf 2KB
  char* p = (char*)d_ws;
  unsigned short* WT = (unsigned short*)p;            p += (size_t)NDIM * KDIM * 2;
  unsigned short* h  = (unsigned short*)p;            p += (size_t)MROWS * KDIM * 2;
  float* partial     = (float*)p;                     p += (size_t)32 * NDIM * 4;
  float* biasf       = (float*)p;

  setup_kernel<<<288, 256, 0, stream>>>(W, gamma, beta, WT, partial);
  kbias2<<<2, 256, 0, stream>>>(b, partial, biasf);
  ln_kernel<<<XROWS / 8, 256, 0, stream>>>(x, h);
  gemm_kernel<<<(MROWS / 128) * 4, 256, 0, stream>>>(h, WT, biasf, out);
}

// Round 14
// 80.587 us; speedup vs baseline: 1.4463x; 1.4463x over previous
//
#include <hip/hip_runtime.h>
#include <hip/hip_bf16.h>
#include <cstdint>

// x: [8,8192,512] f32 -> LN over E=512 -> h=[16384,2048] bf16 (row-major flatten)
// W: [2048,512] f32, b: [512]; out = gelu(h @ W' + b'),
// W' = gamma-folded W (bf16, transposed), b' = b + beta @ W.
#define XROWS   65536
#define E       512
#define MROWS   16384
#define KDIM    2048
#define NDIM    512
#define NT      16        // K-steps of 128

typedef __attribute__((ext_vector_type(4))) float f32x4;
typedef __attribute__((ext_vector_type(8))) unsigned short u16x8;
typedef __attribute__((ext_vector_type(8))) __bf16 bf16x8;

__device__ __forceinline__ unsigned short f2bf(float f) {
  unsigned u = __builtin_bit_cast(unsigned, f);
  u += 0x7FFFu + ((u >> 16) & 1u);   // round-to-nearest-even
  return (unsigned short)(u >> 16);
}

typedef const __attribute__((address_space(1))) unsigned char ga_u8;
typedef __attribute__((address_space(3))) unsigned char ls_u8;
__device__ __forceinline__ void gload16(const void* g, void* l) {
  __builtin_amdgcn_global_load_lds((ga_u8*)g, (ls_u8*)l, 16, 0, 0);
}

// fast gelu (tanh form), |err vs erf form| <= ~3e-3 << 0.094 threshold
__device__ __forceinline__ float gelu_f(float v) {
  float p = v * (2.3022083f + 0.1029432f * (v * v));
  p = fminf(p, 80.0f);
  const float Ee = exp2f(p);
  return v * Ee * __builtin_amdgcn_rcpf(Ee + 1.0f);
}

// ---------------------------------------------------------------------------
// Merged setup: blocks 0..255 -> WT transpose+gamma-fold; 256..287 -> beta
// partials.  WT[n][k] = bf16(gamma[k%512] * W[k][n])
// ---------------------------------------------------------------------------
__global__ __launch_bounds__(256) void setup_kernel(const float* __restrict__ W,
                                                    const float* __restrict__ gamma,
                                                    const float* __restrict__ beta,
                                                    unsigned short* __restrict__ WT,
                                                    float* __restrict__ partial) {
  __shared__ float tile[64][68];
  const int t = threadIdx.x;
  if (blockIdx.x >= 256) {           // beta-fold partials
    const int bk = blockIdx.x - 256;
    float a0 = 0.f, a1 = 0.f;
    for (int k = 0; k < 64; ++k) {
      const int kg = bk * 64 + k;
      const float be = beta[kg & (E - 1)];
      a0 += be * W[(size_t)kg * NDIM + t];
      a1 += be * W[(size_t)kg * NDIM + 256 + t];
    }
    partial[bk * NDIM + t] = a0;
    partial[bk * NDIM + 256 + t] = a1;
    return;
  }
  const int bk = blockIdx.x >> 3;
  const int bn = blockIdx.x & 7;
  const int c4 = (t & 15) * 4;
#pragma unroll
  for (int i = 0; i < 4; ++i) {
    const int r = (t >> 4) + i * 16;
    const f32x4 v = *(const f32x4*)&W[(size_t)(bk * 64 + r) * NDIM + bn * 64 + c4];
    tile[r][c4 + 0] = v.x; tile[r][c4 + 1] = v.y;
    tile[r][c4 + 2] = v.z; tile[r][c4 + 3] = v.w;
  }
  __syncthreads();
#pragma unroll
  for (int j = 0; j < 2; ++j) {
    const int n  = j * 32 + (t >> 3);
    const int kb = (t & 7) * 8;
    const int kg0 = (bk & 7) * 64 + kb;
    const f32x4 g0 = *(const f32x4*)(gamma + kg0);
    const f32x4 g1 = *(const f32x4*)(gamma + kg0 + 4);
    const float gg[8] = {g0.x, g0.y, g0.z, g0.w, g1.x, g1.y, g1.z, g1.w};
    u16x8 o;
#pragma unroll
    for (int q = 0; q < 8; ++q) o[q] = f2bf(gg[q] * tile[kb + q][n]);
    *(u16x8*)&WT[(size_t)(bn * 64 + n) * KDIM + bk * 64 + kb] = o;
  }
}

__global__ __launch_bounds__(256) void kbias2(const float* __restrict__ b,
                                              const float* __restrict__ partial,
                                              float* __restrict__ biasf) {
  const int c = blockIdx.x * 256 + threadIdx.x;
  float s = b[c];
  for (int j = 0; j < 32; ++j) s += partial[j * NDIM + c];
  biasf[c] = s;
}

// ---------------------------------------------------------------------------
// LayerNorm: one wave per TWO x-rows of 512 f32 -> bf16 h (R10-proven, at
// its BW floor ~31us).
// ---------------------------------------------------------------------------
__global__ __launch_bounds__(256, 4) void ln_kernel(const float* __restrict__ x,
                                                    unsigned short* __restrict__ h) {
  const int w = threadIdx.x >> 6, l = threadIdx.x & 63;
  const size_t row = (size_t)blockIdx.x * 8 + w * 2;   // rows row, row+1
  const float* xr = x + row * E + l * 8;
  const f32x4 a0 = *(const f32x4*)xr;
  const f32x4 a1 = *(const f32x4*)(xr + 4);
  const f32x4 b0 = *(const f32x4*)(xr + E);
  const f32x4 b1 = *(const f32x4*)(xr + E + 4);
  float av[8] = {a0.x, a0.y, a0.z, a0.w, a1.x, a1.y, a1.z, a1.w};
  float bv[8] = {b0.x, b0.y, b0.z, b0.w, b1.x, b1.y, b1.z, b1.w};
  float s0 = 0.f, q0 = 0.f, s1 = 0.f, q1 = 0.f;
#pragma unroll
  for (int j = 0; j < 8; ++j) {
    s0 += av[j]; q0 += av[j] * av[j];
    s1 += bv[j]; q1 += bv[j] * bv[j];
  }
#pragma unroll
  for (int off = 32; off > 0; off >>= 1) {
    s0 += __shfl_xor(s0, off); q0 += __shfl_xor(q0, off);
    s1 += __shfl_xor(s1, off); q1 += __shfl_xor(q1, off);
  }
  const float mean0 = s0 * (1.0f / E);
  const float rstd0 = rsqrtf(q0 * (1.0f / E) - mean0 * mean0 + 1e-6f);
  const float nm0   = -mean0 * rstd0;
  const float mean1 = s1 * (1.0f / E);
  const float rstd1 = rsqrtf(q1 * (1.0f / E) - mean1 * mean1 + 1e-6f);
  const float nm1   = -mean1 * rstd1;
  u16x8 o0, o1;
#pragma unroll
  for (int j = 0; j < 8; ++j) {
    o0[j] = f2bf(av[j] * rstd0 + nm0);
    o1[j] = f2bf(bv[j] * rstd1 + nm1);
  }
  *(u16x8*)(h + row * E + l * 8) = o0;
  *(u16x8*)(h + (row + 1) * E + l * 8) = o1;
}

// ---------------------------------------------------------------------------
// GEMM: champion structure with BK=128 (halves barrier count 64->32).
// 128x128 tile, 4 waves (2x2, 64x64/wave), SINGLE 64KB buffer, 2 barriers/
// K-step, gload_lds staging (linear dest + pre-swizzled source; T2 XOR on
// ds_read). Occupancy grid-pinned at 2 blocks/CU (512 wgs) -> 2x64KB LDS ok.
// Rows are 256B wide; swizzle XOR ((row&7)<<4) on byte bits 4-6; frag col
// kk*64 (kk 0..3, bits 6-7) + lhi*16 disjoint -> same bank-free pattern.
// MFMA k-order identical to champion -> absmax must stay 0.03125.
// T1 XCD-chunked bijective swizzle (512 = 8x64).
// ---------------------------------------------------------------------------
__global__ __launch_bounds__(256, 2) void gemm_kernel(const unsigned short* __restrict__ A,
                                                      const unsigned short* __restrict__ Bt,
                                                      const float* __restrict__ biasf,
                                                      float* __restrict__ out) {
  __shared__ char smem[65536];   // A 32KB @0, B 32KB @32768 (128 rows x 256B)
  const int tid = threadIdx.x;
  const int l = tid & 63, w = tid >> 6;
  const int l7 = l & 7, l15 = l & 15, lhi = l >> 4;
  const int wr = w >> 1, wc = w & 1;

  // XCD chunking: grid 512 = 8 XCDs x 64; bn in low 2 bits of wg
  const int wg = ((blockIdx.x & 7) << 6) | (blockIdx.x >> 3);
  const int bn = wg & 3;
  const int bm = wg >> 2;
  const size_t arow0 = (size_t)bm * 128;
  const int    brow0 = bn * 128;

  // staging: call i covers rows i*16 + (tid>>4), 16B unit u = tid&15 of the
  // 256B K-window; source byte col pre-swizzled: (u*16) ^ ((row&7)<<4).
  // LDS dest for call i = i*4096 + tid*16 (wave-linear ✓).
  const int srow = tid >> 4;                       // 0..15
  const int swz  = ((tid & 15) * 16) ^ ((srow & 7) << 4);
  const char* gA = (const char*)A  + ((size_t)(arow0 + srow) * KDIM) * 2 + swz;
  const char* gB = (const char*)Bt + ((size_t)(brow0 + srow) * KDIM) * 2 + swz;

  f32x4 acc[4][4];
#pragma unroll
  for (int m = 0; m < 4; ++m)
#pragma unroll
    for (int n = 0; n < 4; ++n) acc[m][n] = (f32x4){0.f, 0.f, 0.f, 0.f};

  // frag-read swizzled base (kk adds bits 6-7, disjoint from lhi bits 4-5;
  // XOR with (row&7)<<4 = l7*16 consistent with staging)
  const int cs0 = (lhi * 16) ^ (l7 * 16);

  for (int t = 0; t < NT; ++t) {
    __syncthreads();               // all waves done reading buffer
    {
      const char* pa = gA + (size_t)t * 256;
      const char* pb = gB + (size_t)t * 256;
#pragma unroll
      for (int i = 0; i < 8; ++i) {
        gload16(pa + (size_t)i * 16 * KDIM * 2, smem + i * 4096 + tid * 16);
        gload16(pb + (size_t)i * 16 * KDIM * 2, smem + 32768 + i * 4096 + tid * 16);
      }
    }
    __syncthreads();               // drains vmcnt(0): staged data visible
#pragma unroll
    for (int kk = 0; kk < 4; ++kk) {
      const int co = cs0 ^ (kk * 64);
      bf16x8 av[4], bv[4];
#pragma unroll
      for (int m = 0; m < 4; ++m)
        av[m] = *(const bf16x8*)(smem + (wr * 64 + m * 16 + l15) * 256 + co);
#pragma unroll
      for (int n = 0; n < 4; ++n)
        bv[n] = *(const bf16x8*)(smem + 32768 + (wc * 64 + n * 16 + l15) * 256 + co);
#pragma unroll
      for (int m = 0; m < 4; ++m)
#pragma unroll
        for (int n = 0; n < 4; ++n)
          acc[m][n] = __builtin_amdgcn_mfma_f32_16x16x32_bf16(av[m], bv[n],
                                                              acc[m][n], 0, 0, 0);
    }
  }

  // epilogue: bias + fast gelu. C/D layout (m89): col = l&15, row = (l>>4)*4+reg
#pragma unroll
  for (int n = 0; n < 4; ++n) {
    const int col = brow0 + wc * 64 + n * 16 + l15;
    const float bb = biasf[col];
#pragma unroll
    for (int m = 0; m < 4; ++m) {
      const size_t rbase = arow0 + wr * 64 + m * 16 + lhi * 4;
#pragma unroll
      for (int r = 0; r < 4; ++r) {
        const float v = acc[m][n][r] + bb;
        out[(rbase + r) * NDIM + col] = gelu_f(v);
      }
    }
  }
}

// ---------------------------------------------------------------------------
extern "C" void kernel_launch(void* const* d_in, const int* in_sizes, int n_in,
                              void* d_out, int out_size, void* d_ws, size_t ws_size,
                              hipStream_t stream) {
  const float* x     = (const float*)d_in[0];
  const float* gamma = (const float*)d_in[1];
  const float* beta  = (const float*)d_in[2];
  const float* W     = (const float*)d_in[3];
  const float* b     = (const float*)d_in[4];
  float* out = (float*)d_out;

  // ws layout: WT 2MB | h 64MB | partial 64KB | biasf 2KB
  char* p = (char*)d_ws;
  unsigned short* WT = (unsigned short*)p;            p += (size_t)NDIM * KDIM * 2;
  unsigned short* h  = (unsigned short*)p;            p += (size_t)MROWS * KDIM * 2;
  float* partial     = (float*)p;                     p += (size_t)32 * NDIM * 4;
  float* biasf       = (float*)p;

  setup_kernel<<<288, 256, 0, stream>>>(W, gamma, beta, WT, partial);
  kbias2<<<2, 256, 0, stream>>>(b, partial, biasf);
  ln_kernel<<<XROWS / 8, 256, 0, stream>>>(x, h);
  gemm_kernel<<<(MROWS / 128) * 4, 256, 0, stream>>>(h, WT, biasf, out);
}